// Round 12
// baseline (405.098 us; speedup 1.0000x reference)
//
#include <hip/hip_runtime.h>

typedef float  f32x4  __attribute__((ext_vector_type(4)));
typedef __bf16 bf16x8 __attribute__((ext_vector_type(8)));
typedef unsigned short ushort_t;

#define N_PTS 4096
#define R_ROIS 128
#define M_GP  27648
#define LDS_FENCE() asm volatile("s_waitcnt lgkmcnt(0)" ::: "memory")

// ---------------- workspace layout (bytes), total 13,763,072 ----------------
static constexpr size_t OFF_GP     = 0;          // 331,776
// A-fragment arrays (pool output, s1 input): [432][128][32] u16 each
static constexpr size_t OFF_PH     = 331776;     // 3,538,944
static constexpr size_t OFF_PL     = 3870720;    // 3,538,944 (end 7,409,664)
// h1/h2 overlay the A-frag region (dead after s1 GEMM):
static constexpr size_t OFF_H1H    = 331776;     // 3*131072*2 = 786,432 (frag u16)
static constexpr size_t OFF_H1L    = 1118208;    // 786,432
static constexpr size_t OFF_H2S    = 1904640;    // 3*128*512*4 = 786,432 (end 2,691,072)
static constexpr size_t OFF_PART   = 7409664;    // 4,194,304 (end 11,603,968)
//   pool-phase overlays inside PART (all dead before GEMM partials):
static constexpr size_t OFF_CAND   = OFF_PART;   // 2,097,152
static constexpr size_t OFF_F      = 9506816;    // 1,048,576
static constexpr size_t OFF_XYZ4   = 10555392;   // 65,536 (end 10,620,928)
static constexpr size_t OFF_NCAND  = 11603968;   // 512
static constexpr size_t OFF_W1TH   = 11604480;   // 10752*2
static constexpr size_t OFF_W1TL   = 11625984;   // 10752*2
static constexpr size_t OFF_W2TH   = 11647488;   // 4608*2
static constexpr size_t OFF_W2TL   = 11656704;   // 4608*2 (end 11,665,920)
// fhi/flo live until f_gemm; t1/sfc (FC phase) overlay them:
static constexpr size_t OFF_FHI    = 11665920;   // 1,048,576
static constexpr size_t OFF_FLO    = 12714496;   // 1,048,576 (end 13,763,072)
static constexpr size_t OFF_T1H    = 11665920;   // 262,144 (t1 frag u16)
static constexpr size_t OFF_T1L    = 11928064;   // 262,144
static constexpr size_t OFF_SFCH   = 12190208;   // 131,072 (sfc frag u16)
static constexpr size_t OFF_SFCL   = 12321280;   // 131,072 (end 12,452,352)

static __device__ inline ushort_t f2bf(float f) {
    unsigned int u = __float_as_uint(f);
    unsigned int r = u + 0x7FFFu + ((u >> 16) & 1u);
    return (ushort_t)(r >> 16);
}
static __device__ inline float bf2f(ushort_t h) {
    return __uint_as_float(((unsigned int)h) << 16);
}
static __device__ inline ushort_t bfbits(__bf16 h) {
    return __builtin_bit_cast(ushort_t, h);
}

// ---------------- merged prep: gps | weights | feats | xyz4 | roi cand ----
__global__ __launch_bounds__(256) void prep_all_k(
    const float* __restrict__ rois, const float* __restrict__ xyz,
    const float* __restrict__ feats, const float* __restrict__ w1,
    const float* __restrict__ w2, float* __restrict__ gp,
    ushort_t* __restrict__ fhi, ushort_t* __restrict__ flo,
    ushort_t* __restrict__ w1th, ushort_t* __restrict__ w1tl,
    ushort_t* __restrict__ w2th, ushort_t* __restrict__ w2tl,
    float4* __restrict__ xyz4,
    int* __restrict__ cand, int* __restrict__ ncand) {
    int b = blockIdx.x, tid = threadIdx.x;
    if (b < 108) {                       // ---- grid points
        int m = b * 256 + tid;
        int r = m / 216, t = m % 216;
        int gi = t / 36, gj = (t / 6) % 6, gk = t % 6;
        const float* roi = rois + r * 7;
        float sx = roi[3], sy = roi[4], sz = roi[5];
        float lx = ((float)gi + 0.5f) / 6.0f * sx - sx * 0.5f;
        float ly = ((float)gj + 0.5f) / 6.0f * sy - sy * 0.5f;
        float lz = ((float)gk + 0.5f) / 6.0f * sz - sz * 0.5f;
        float c = cosf(roi[6]), s = sinf(roi[6]);
        gp[m * 3 + 0] = lx * c - ly * s + roi[0];
        gp[m * 3 + 1] = lx * s + ly * c + roi[1];
        gp[m * 3 + 2] = lz + roi[2];
    } else if (b < 150) {                // ---- weight prep (permuted transpose + hi/lo)
        int t = (b - 108) * 256 + tid;   // t < 10752
        {
            int col = t / 168, p = t % 168;
            float v = (p < 128) ? w1[(3 + p) * 64 + col]
                    : (p < 131) ? w1[(p - 128) * 64 + col] : 0.f;
            ushort_t hi = f2bf(v);
            w1th[t] = hi;
            w1tl[t] = f2bf(v - bf2f(hi));
        }
        if (t < 4608) {
            int col = t / 72, k = t % 72;
            float v = (k < 64) ? w2[k * 64 + col] : 0.f;
            ushort_t hi = f2bf(v);
            w2th[t] = hi;
            w2tl[t] = f2bf(v - bf2f(hi));
        }
    } else if (b < 2198) {               // ---- feats -> hi/lo bf16
        int i = (b - 150) * 256 + tid;   // i < 524288
        float v = feats[i];
        __bf16 h = (__bf16)v;
        fhi[i] = bfbits(h);
        flo[i] = bfbits((__bf16)(v - (float)h));
    } else if (b < 2214) {               // ---- xyz -> float4 pack
        int i = (b - 2198) * 256 + tid;  // i < 4096
        xyz4[i] = make_float4(xyz[i * 3 + 0], xyz[i * 3 + 1], xyz[i * 3 + 2], 0.f);
    } else {                             // ---- per-RoI candidate lists (4 waves/block)
        int r = (b - 2214) * 4 + (tid >> 6);
        int lane = tid & 63;
        const float* roi = rois + r * 7;
        float cx = roi[0], cy = roi[1], cz = roi[2];
        float sx = roi[3], sy = roi[4], sz = roi[5];
        float Rc = 0.8f + 0.4166667f * sqrtf(sx * sx + sy * sy + sz * sz) + 0.01f;
        float Rc2 = Rc * Rc;
        int* cl = cand + (size_t)r * N_PTS;
        int cnt = 0;
        for (int base = 0; base < N_PTS; base += 64) {
            int i = base + lane;
            float dx = xyz[i * 3 + 0] - cx;
            float dy = xyz[i * 3 + 1] - cy;
            float dz = xyz[i * 3 + 2] - cz;
            bool in = dx * dx + dy * dy + dz * dz < Rc2;
            unsigned long long ball = __ballot(in);
            int before = __popcll(ball & ((1ull << lane) - 1ull));
            if (in) cl[cnt + before] = i;
            cnt += __popcll(ball);
        }
        if (lane == 0) ncand[r] = cnt;
    }
}

// ---------------- F = feats @ W1f (split-bf16 MFMA), 4096x64 f32 ----------
__global__ __launch_bounds__(256) void f_gemm_k(
    const ushort_t* __restrict__ fhi, const ushort_t* __restrict__ flo,
    const ushort_t* __restrict__ w1th, const ushort_t* __restrict__ w1tl,
    float* __restrict__ F) {
    int tid = threadIdx.x;
    int w = tid >> 6, lane = tid & 63;
    int row = lane & 15, grp = lane >> 4;
    int m0 = blockIdx.x * 64 + w * 16;

    f32x4 acc[4];
#pragma unroll
    for (int nt = 0; nt < 4; nt++) acc[nt] = {0.f, 0.f, 0.f, 0.f};

#pragma unroll
    for (int ks = 0; ks < 4; ks++) {
        size_t ao = (size_t)(m0 + row) * 128 + ks * 32 + grp * 8;
        bf16x8 ah = *(const bf16x8*)&fhi[ao];
        bf16x8 al = *(const bf16x8*)&flo[ao];
#pragma unroll
        for (int nt = 0; nt < 4; nt++) {
            int bo = (nt * 16 + row) * 168 + ks * 32 + grp * 8;
            bf16x8 bh = *(const bf16x8*)&w1th[bo];
            bf16x8 bl = *(const bf16x8*)&w1tl[bo];
            acc[nt] = __builtin_amdgcn_mfma_f32_16x16x32_bf16(ah, bh, acc[nt], 0, 0, 0);
            acc[nt] = __builtin_amdgcn_mfma_f32_16x16x32_bf16(al, bh, acc[nt], 0, 0, 0);
            acc[nt] = __builtin_amdgcn_mfma_f32_16x16x32_bf16(ah, bl, acc[nt], 0, 0, 0);
        }
    }
#pragma unroll
    for (int nt = 0; nt < 4; nt++)
#pragma unroll
        for (int reg = 0; reg < 4; reg++)
            F[(size_t)(m0 + grp * 4 + reg) * 64 + nt * 16 + row] = acc[nt][reg];
}

// ---------------- pool v5: SHARED 4-gp scan + F-gather + stage2 MFMA -------
__global__ __launch_bounds__(64) void grid_pool_v5_k(
    const float4* __restrict__ xyz4, const float* __restrict__ F,
    const float* __restrict__ gp, const int* __restrict__ cand,
    const int* __restrict__ ncand, const float* __restrict__ w_m1,
    const ushort_t* __restrict__ w2th, const ushort_t* __restrict__ w2tl,
    ushort_t* __restrict__ Afh, ushort_t* __restrict__ Afl) {
    __shared__ int s_idx[4][16];
    int lane = threadIdx.x;
    const float R2 = (float)(0.8 * 0.8);
    int row = lane & 15, grp = lane >> 4;
    int m0 = blockIdx.x * 4;
    int r = m0 / 216;                    // shared RoI for all 4 gps

    float gxv[4], gyv[4], gzv[4];
#pragma unroll
    for (int g = 0; g < 4; g++) {
        int m = m0 + g;
        gxv[g] = gp[m * 3 + 0];
        gyv[g] = gp[m * 3 + 1];
        gzv[g] = gp[m * 3 + 2];
    }

    int nc = ncand[r];
    const int* cl = cand + (size_t)r * N_PTS;
    int cnt0 = 0, cnt1 = 0, cnt2 = 0, cnt3 = 0;
    for (int base = 0; base < nc; base += 64) {
        int t = base + lane;
        float px = 1e30f, py = 1e30f, pz = 1e30f;
        int i = 0;
        if (t < nc) {
            i = cl[t];
            float4 p = xyz4[i];
            px = p.x; py = p.y; pz = p.z;
        }
#pragma unroll
        for (int g = 0; g < 4; g++) {
            float dx = px - gxv[g], dy = py - gyv[g], dz = pz - gzv[g];
            bool in = dx * dx + dy * dy + dz * dz < R2;
            unsigned long long ball = __ballot(in);
            int before = __popcll(ball & ((1ull << lane) - 1ull));
            int cnt = (g == 0) ? cnt0 : (g == 1) ? cnt1 : (g == 2) ? cnt2 : cnt3;
            int pos = cnt + before;
            if (in && pos < 16) s_idx[g][pos] = i;
            int add = __popcll(ball);
            if (g == 0) cnt0 += add; else if (g == 1) cnt1 += add;
            else if (g == 2) cnt2 += add; else cnt3 += add;
        }
        if (cnt0 >= 16 && cnt1 >= 16 && cnt2 >= 16 && cnt3 >= 16) break;
    }
    LDS_FENCE();

    bool empty[4];
#pragma unroll
    for (int g = 0; g < 4; g++) {
        int cnt = (g == 0) ? cnt0 : (g == 1) ? cnt1 : (g == 2) ? cnt2 : cnt3;
        int c = min(cnt, 16);
        empty[g] = (c == 0);
        if (lane == 0) {
            if (c == 0) {
                for (int p = 0; p < 16; p++) s_idx[g][p] = 0;
            } else {
                int f = s_idx[g][0];
                for (int p = c; p < 16; p++) s_idx[g][p] = f;
            }
        }
    }
    LDS_FENCE();

    int pi[4];
    float rx[4], ry[4], rz[4];
#pragma unroll
    for (int g = 0; g < 4; g++) {
        pi[g] = s_idx[g][row];
        float4 p = xyz4[pi[g]];
        rx[g] = p.x - gxv[g];
        ry[g] = p.y - gyv[g];
        rz[g] = p.z - gzv[g];
    }

    f32x4 p[4][4];
#pragma unroll
    for (int g = 0; g < 4; g++)
#pragma unroll
        for (int nt = 0; nt < 4; nt++) p[g][nt] = {0.f, 0.f, 0.f, 0.f};

#pragma unroll
    for (int ks = 0; ks < 2; ks++) {
        float w1r0[8], w1r1[8], w1r2[8];
        {
            const float* wp = w_m1 + ks * 32 + grp * 8;
            *(float4*)&w1r0[0] = *(const float4*)(wp);
            *(float4*)&w1r0[4] = *(const float4*)(wp + 4);
            *(float4*)&w1r1[0] = *(const float4*)(wp + 64);
            *(float4*)&w1r1[4] = *(const float4*)(wp + 68);
            *(float4*)&w1r2[0] = *(const float4*)(wp + 128);
            *(float4*)&w1r2[4] = *(const float4*)(wp + 132);
        }
        bf16x8 zah[4], zal[4];
#pragma unroll
        for (int g = 0; g < 4; g++) {
            const float* Fr = F + (size_t)pi[g] * 64 + ks * 32 + grp * 8;
            float fv[8];
            *(float4*)&fv[0] = *(const float4*)Fr;
            *(float4*)&fv[4] = *(const float4*)(Fr + 4);
            bf16x8 hh, ll;
#pragma unroll
            for (int j = 0; j < 8; j++) {
                float zv = fv[j] + rx[g] * w1r0[j] + ry[g] * w1r1[j] + rz[g] * w1r2[j];
                float v = fmaxf(zv, 0.f);
                __bf16 h = (__bf16)v;
                hh[j] = h;
                ll[j] = (__bf16)(v - (float)h);
            }
            zah[g] = hh; zal[g] = ll;
        }
#pragma unroll
        for (int nt = 0; nt < 4; nt++) {
            int bo = (nt * 16 + row) * 72 + ks * 32 + grp * 8;
            bf16x8 bh = *(const bf16x8*)&w2th[bo];
            bf16x8 bl = *(const bf16x8*)&w2tl[bo];
#pragma unroll
            for (int g = 0; g < 4; g++) {
                p[g][nt] = __builtin_amdgcn_mfma_f32_16x16x32_bf16(zah[g], bh, p[g][nt], 0, 0, 0);
                p[g][nt] = __builtin_amdgcn_mfma_f32_16x16x32_bf16(zal[g], bh, p[g][nt], 0, 0, 0);
                p[g][nt] = __builtin_amdgcn_mfma_f32_16x16x32_bf16(zah[g], bl, p[g][nt], 0, 0, 0);
            }
        }
    }

#pragma unroll
    for (int g = 0; g < 4; g++) {
        int m = m0 + g;
        int t = m % 216;
#pragma unroll
        for (int nt = 0; nt < 4; nt++) {
            float mv = fmaxf(fmaxf(fmaxf(p[g][nt][0], p[g][nt][1]),
                                   fmaxf(p[g][nt][2], p[g][nt][3])), 0.f);
            mv = fmaxf(mv, __shfl_xor(mv, 16));
            mv = fmaxf(mv, __shfl_xor(mv, 32));
            if (grp == 0) {
                float v = empty[g] ? 0.f : mv;
                __bf16 h = (__bf16)v;
                int kt = t * 2 + (nt >> 1);
                size_t o = ((size_t)kt * 128 + r) * 32 + (nt & 1) * 16 + row;
                Afh[o] = bfbits(h);
                Afl[o] = bfbits((__bf16)(v - (float)h));
            }
        }
    }
}

// ---------------- generalized streaming split-K MFMA GEMM -------------------
// A in frag layout [Kt/32][128][32] u16 hi/lo; B f32 [Kt][N] row-major.
// BM=64, BN=32, BK=32 per iter, depth-2 register prefetch, b64 LDS writes.
// grid (N/32, 2, heads*S). Partials P[z][128][N], z = head*S + s.
__global__ __launch_bounds__(256) void gemm_stream_k(
    const ushort_t* __restrict__ A_h, const ushort_t* __restrict__ A_l,
    size_t a_stride,
    const float* __restrict__ B0, const float* __restrict__ B1,
    const float* __restrict__ B2,
    float* __restrict__ P, int N, int Kt, int S) {
    __shared__ __attribute__((aligned(16))) ushort_t Bs_h[32][40];
    __shared__ __attribute__((aligned(16))) ushort_t Bs_l[32][40];
    int tid = threadIdx.x;
    int w = tid >> 6, lane = tid & 63;
    int row = lane & 15, grp = lane >> 4;
    int z = blockIdx.z, head = z / S, s = z % S;
    int n0 = blockIdx.x * 32, m0 = blockIdx.y * 64;
    const float* B = (head == 0) ? B0 : (head == 1) ? B1 : B2;
    const ushort_t* Ah = A_h + (size_t)head * a_stride;
    const ushort_t* Al = A_l + (size_t)head * a_stride;
    const int STEPS = Kt / (32 * S);
    int kt0 = s * STEPS;                 // in 32-k tile units
    int nl = tid & 31, kg = tid >> 5;    // staging: n = n0+nl, k = kg*4+j

    f32x4 acc[2];
    acc[0] = {0.f, 0.f, 0.f, 0.f};
    acc[1] = {0.f, 0.f, 0.f, 0.f};

    int arow = m0 + w * 16 + row;

    float bv[2][4];
    bf16x8 ahv[2], alv[2];

    auto loadB = [&](int t, float* dst) {
        const float* bp = B + (size_t)((kt0 + t) * 32 + kg * 4) * N + n0 + nl;
        dst[0] = bp[0];
        dst[1] = bp[(size_t)N];
        dst[2] = bp[(size_t)2 * N];
        dst[3] = bp[(size_t)3 * N];
    };
    auto loadA = [&](int t, bf16x8* ah, bf16x8* al) {
        size_t ao = ((size_t)(kt0 + t) * 128 + arow) * 32 + grp * 8;
        *ah = *(const bf16x8*)&Ah[ao];
        *al = *(const bf16x8*)&Al[ao];
    };

    loadB(0, bv[0]);
    loadA(0, &ahv[0], &alv[0]);
    if (STEPS > 1) { loadB(1, bv[1]); loadA(1, &ahv[1], &alv[1]); }

    for (int t = 0; t < STEPS; ++t) {
        int cur = t & 1;
        {   // stage: 4 k-contiguous values -> one b64 write per array
            ushort_t hs[4], ls[4];
#pragma unroll
            for (int j = 0; j < 4; j++) {
                float v = bv[cur][j];
                __bf16 h = (__bf16)v;
                hs[j] = bfbits(h);
                ls[j] = bfbits((__bf16)(v - (float)h));
            }
            uint2 hw = make_uint2((unsigned)hs[0] | ((unsigned)hs[1] << 16),
                                  (unsigned)hs[2] | ((unsigned)hs[3] << 16));
            uint2 lw = make_uint2((unsigned)ls[0] | ((unsigned)ls[1] << 16),
                                  (unsigned)ls[2] | ((unsigned)ls[3] << 16));
            *(uint2*)&Bs_h[nl][kg * 4] = hw;
            *(uint2*)&Bs_l[nl][kg * 4] = lw;
        }
        __syncthreads();
        bf16x8 ah = ahv[cur], al = alv[cur];
#pragma unroll
        for (int ni = 0; ni < 2; ni++) {
            bf16x8 bh = *(const bf16x8*)&Bs_h[ni * 16 + row][grp * 8];
            bf16x8 bl = *(const bf16x8*)&Bs_l[ni * 16 + row][grp * 8];
            acc[ni] = __builtin_amdgcn_mfma_f32_16x16x32_bf16(ah, bh, acc[ni], 0, 0, 0);
            acc[ni] = __builtin_amdgcn_mfma_f32_16x16x32_bf16(al, bh, acc[ni], 0, 0, 0);
            acc[ni] = __builtin_amdgcn_mfma_f32_16x16x32_bf16(ah, bl, acc[ni], 0, 0, 0);
        }
        if (t + 2 < STEPS) {             // refill slot cur for iteration t+2
            loadB(t + 2, bv[cur]);
            loadA(t + 2, &ahv[cur], &alv[cur]);
        }
        __syncthreads();
    }

    size_t pb = (size_t)z * 128 * N;
#pragma unroll
    for (int ni = 0; ni < 2; ni++)
#pragma unroll
        for (int reg = 0; reg < 4; reg++) {
            int mrow = m0 + w * 16 + grp * 4 + reg;
            P[pb + (size_t)mrow * N + n0 + ni * 16 + row] = acc[ni][reg];
        }
}

// ---------------- reduce partials + relu -> frag-layout hi/lo (or f32) ----
// P[z][128][Nn], z = head*S+s. Frag out: off = h*MNper + ((n>>5)*128+m)*32+(n&31)
__global__ __launch_bounds__(256) void reduce_frag_k(
    const float* __restrict__ P, ushort_t* __restrict__ C_h,
    ushort_t* __restrict__ C_l, float* __restrict__ C_f, int out_f32,
    int MNper, int S, int heads, int Nn) {
    int i = blockIdx.x * 256 + threadIdx.x;
    if (i >= heads * MNper) return;
    int h = i / MNper, j = i % MNper;
    float v = 0.f;
    for (int s = 0; s < S; s++) v += P[((size_t)(h * S + s)) * MNper + j];
    v = fmaxf(v, 0.f);
    if (out_f32) {
        C_f[i] = v;
        return;
    }
    int m = j / Nn, n = j % Nn;
    size_t off = (size_t)h * MNper + ((size_t)(n >> 5) * 128 + m) * 32 + (n & 31);
    __bf16 hh = (__bf16)v;
    C_h[off] = bfbits(hh);
    C_l[off] = bfbits((__bf16)(v - (float)hh));
}

// ---------------- final head projections (merged) ----------------
__global__ __launch_bounds__(256) void head_out3_k(
    const float* __restrict__ h2s, const float* __restrict__ w_c3,
    const float* __restrict__ w_i3, const float* __restrict__ w_r3,
    const float* __restrict__ b_c3, const float* __restrict__ b_i3,
    const float* __restrict__ b_r3, float* __restrict__ out) {
    int t = blockIdx.x * 256 + threadIdx.x;
    if (t >= 128 * 9) return;
    int r = t / 9, col = t % 9;
    int head = (col == 0) ? 0 : (col == 1) ? 1 : 2;
    int p = (col < 2) ? 0 : col - 2;
    int Pn = (head == 2) ? 7 : 1;
    const float* h2 = h2s + (size_t)head * (128 * 512) + (size_t)r * 512;
    const float* w3 = (head == 0) ? w_c3 : (head == 1) ? w_i3 : w_r3;
    float acc = ((head == 0) ? b_c3 : (head == 1) ? b_i3 : b_r3)[p];
    for (int j = 0; j < 512; j++) acc += h2[j] * w3[j * Pn + p];
    out[r * 9 + col] = acc;
}

extern "C" void kernel_launch(void* const* d_in, const int* in_sizes, int n_in,
                              void* d_out, int out_size, void* d_ws, size_t ws_size,
                              hipStream_t stream) {
    const float* xyz   = (const float*)d_in[0];
    const float* feats = (const float*)d_in[1];
    const float* rois  = (const float*)d_in[2];
    const float* w_m1  = (const float*)d_in[3];
    const float* w_m2  = (const float*)d_in[4];
    const float* w_s1  = (const float*)d_in[5];
    const float* w_s2  = (const float*)d_in[6];
    const float* w_c1  = (const float*)d_in[7];
    const float* w_c2  = (const float*)d_in[8];
    const float* w_c3  = (const float*)d_in[9];
    const float* b_c3  = (const float*)d_in[10];
    const float* w_i1  = (const float*)d_in[11];
    const float* w_i2  = (const float*)d_in[12];
    const float* w_i3  = (const float*)d_in[13];
    const float* b_i3  = (const float*)d_in[14];
    const float* w_r1  = (const float*)d_in[15];
    const float* w_r2  = (const float*)d_in[16];
    const float* w_r3  = (const float*)d_in[17];
    const float* b_r3  = (const float*)d_in[18];
    float* out = (float*)d_out;

    char* ws = (char*)d_ws;
    float*    gp     = (float*)(ws + OFF_GP);
    ushort_t* afh    = (ushort_t*)(ws + OFF_PH);
    ushort_t* afl    = (ushort_t*)(ws + OFF_PL);
    float*    part   = (float*)(ws + OFF_PART);
    int*      cand   = (int*)(ws + OFF_CAND);
    float*    F      = (float*)(ws + OFF_F);
    float4*   xyz4   = (float4*)(ws + OFF_XYZ4);
    int*      ncand  = (int*)(ws + OFF_NCAND);
    ushort_t* w1th   = (ushort_t*)(ws + OFF_W1TH);
    ushort_t* w1tl   = (ushort_t*)(ws + OFF_W1TL);
    ushort_t* w2th   = (ushort_t*)(ws + OFF_W2TH);
    ushort_t* w2tl   = (ushort_t*)(ws + OFF_W2TL);
    ushort_t* fhi    = (ushort_t*)(ws + OFF_FHI);
    ushort_t* flo    = (ushort_t*)(ws + OFF_FLO);
    ushort_t* t1h    = (ushort_t*)(ws + OFF_T1H);
    ushort_t* t1l    = (ushort_t*)(ws + OFF_T1L);
    ushort_t* sfch   = (ushort_t*)(ws + OFF_SFCH);
    ushort_t* sfcl   = (ushort_t*)(ws + OFF_SFCL);
    ushort_t* h1h    = (ushort_t*)(ws + OFF_H1H);
    ushort_t* h1l    = (ushort_t*)(ws + OFF_H1L);
    float*    h2s    = (float*)(ws + OFF_H2S);

    // 1. all prep
    hipLaunchKernelGGL(prep_all_k, dim3(2246), dim3(256), 0, stream,
                       rois, xyz, feats, w_m1, w_m2, gp, fhi, flo,
                       w1th, w1tl, w2th, w2tl, xyz4, cand, ncand);
    // 2. F = feats @ W1f
    hipLaunchKernelGGL(f_gemm_k, dim3(64), dim3(256), 0, stream,
                       fhi, flo, w1th, w1tl, F);
    // 3. pool -> A_frag hi/lo (shared 4-gp scan)
    hipLaunchKernelGGL(grid_pool_v5_k, dim3(M_GP / 4), dim3(64), 0, stream,
                       xyz4, F, gp, cand, ncand, w_m1, w2th, w2tl, afh, afl);
    // 4. s1: Afrag(13824) @ w_s1 -> partials (S=8, 512 blocks)
    hipLaunchKernelGGL(gemm_stream_k, dim3(32, 2, 8), dim3(256), 0, stream,
                       afh, afl, (size_t)0, w_s1, w_s1, w_s1, part, 1024, 13824, 8);
    hipLaunchKernelGGL(reduce_frag_k, dim3(512), dim3(256), 0, stream,
                       part, t1h, t1l, (float*)nullptr, 0, 128 * 1024, 8, 1, 1024);
    // 5. s2: t1frag(1024) @ w_s2 -> sfc frag (S=8, 256 blocks)
    hipLaunchKernelGGL(gemm_stream_k, dim3(16, 2, 8), dim3(256), 0, stream,
                       t1h, t1l, (size_t)0, w_s2, w_s2, w_s2, part, 512, 1024, 8);
    hipLaunchKernelGGL(reduce_frag_k, dim3(256), dim3(256), 0, stream,
                       part, sfch, sfcl, (float*)nullptr, 0, 128 * 512, 8, 1, 512);
    // 6. heads L1: sfcfrag(512) @ {w_c1,w_i1,w_r1} -> h1 frag (S=2, 384 blocks)
    hipLaunchKernelGGL(gemm_stream_k, dim3(32, 2, 6), dim3(256), 0, stream,
                       sfch, sfcl, (size_t)0, w_c1, w_i1, w_r1, part, 1024, 512, 2);
    hipLaunchKernelGGL(reduce_frag_k, dim3(1536), dim3(256), 0, stream,
                       part, h1h, h1l, (float*)nullptr, 0, 128 * 1024, 2, 3, 1024);
    // 7. heads L2: h1frag(1024) @ {w_c2,w_i2,w_r2} -> h2s f32 (S=4, 384 blocks)
    hipLaunchKernelGGL(gemm_stream_k, dim3(16, 2, 12), dim3(256), 0, stream,
                       h1h, h1l, (size_t)131072, w_c2, w_i2, w_r2, part, 512, 1024, 4);
    hipLaunchKernelGGL(reduce_frag_k, dim3(768), dim3(256), 0, stream,
                       part, (ushort_t*)nullptr, (ushort_t*)nullptr, h2s, 1,
                       128 * 512, 4, 3, 512);
    // 8. final projections
    hipLaunchKernelGGL(head_out3_k, dim3(5), dim3(256), 0, stream,
                       h2s, w_c3, w_i3, w_r3, b_c3, b_i3, b_r3, out);
}

// Round 13
// 167.282 us; speedup vs baseline: 2.4216x; 2.4216x over previous
//
#include <hip/hip_runtime.h>

typedef float  f32x4  __attribute__((ext_vector_type(4)));
typedef __bf16 bf16x8 __attribute__((ext_vector_type(8)));
typedef unsigned short ushort_t;

#define N_PTS 4096
#define R_ROIS 128
#define M_GP  27648
#define LDS_FENCE() asm volatile("s_waitcnt lgkmcnt(0)" ::: "memory")

// ---------------- workspace layout (bytes), total 13,763,072 ----------------
static constexpr size_t OFF_GP     = 0;          // 331,776
static constexpr size_t OFF_PH     = 331776;     // A-frag hi [432][128][32] u16
static constexpr size_t OFF_PL     = 3870720;    // A-frag lo (end 7,409,664)
static constexpr size_t OFF_H1H    = 331776;     // h1 frag hi (overlay, post-s1)
static constexpr size_t OFF_H1L    = 1118208;
static constexpr size_t OFF_H2S    = 1904640;    // h2 f32 (end 2,691,072)
static constexpr size_t OFF_PART   = 7409664;    // partials (end 11,603,968)
static constexpr size_t OFF_CAND   = OFF_PART;   // pool-phase overlay
static constexpr size_t OFF_F      = 9506816;
static constexpr size_t OFF_XYZ4   = 10555392;   // (end 10,620,928)
static constexpr size_t OFF_NCAND  = 11603968;
static constexpr size_t OFF_W1TH   = 11604480;
static constexpr size_t OFF_W1TL   = 11625984;
static constexpr size_t OFF_W2TH   = 11647488;
static constexpr size_t OFF_W2TL   = 11656704;   // (end 11,665,920)
static constexpr size_t OFF_FHI    = 11665920;
static constexpr size_t OFF_FLO    = 12714496;   // (end 13,763,072)
static constexpr size_t OFF_T1H    = 11665920;   // t1 frag (overlay, post-f_gemm)
static constexpr size_t OFF_T1L    = 11928064;
static constexpr size_t OFF_SFCH   = 12190208;
static constexpr size_t OFF_SFCL   = 12321280;   // (end 12,452,352)

static __device__ inline ushort_t f2bf(float f) {
    unsigned int u = __float_as_uint(f);
    unsigned int r = u + 0x7FFFu + ((u >> 16) & 1u);
    return (ushort_t)(r >> 16);
}
static __device__ inline float bf2f(ushort_t h) {
    return __uint_as_float(((unsigned int)h) << 16);
}
static __device__ inline ushort_t bfbits(__bf16 h) {
    return __builtin_bit_cast(ushort_t, h);
}

// ---------------- merged prep: gps | weights | feats | xyz4 | roi cand ----
__global__ __launch_bounds__(256) void prep_all_k(
    const float* __restrict__ rois, const float* __restrict__ xyz,
    const float* __restrict__ feats, const float* __restrict__ w1,
    const float* __restrict__ w2, float* __restrict__ gp,
    ushort_t* __restrict__ fhi, ushort_t* __restrict__ flo,
    ushort_t* __restrict__ w1th, ushort_t* __restrict__ w1tl,
    ushort_t* __restrict__ w2th, ushort_t* __restrict__ w2tl,
    float4* __restrict__ xyz4,
    int* __restrict__ cand, int* __restrict__ ncand) {
    int b = blockIdx.x, tid = threadIdx.x;
    if (b < 108) {                       // ---- grid points
        int m = b * 256 + tid;
        int r = m / 216, t = m % 216;
        int gi = t / 36, gj = (t / 6) % 6, gk = t % 6;
        const float* roi = rois + r * 7;
        float sx = roi[3], sy = roi[4], sz = roi[5];
        float lx = ((float)gi + 0.5f) / 6.0f * sx - sx * 0.5f;
        float ly = ((float)gj + 0.5f) / 6.0f * sy - sy * 0.5f;
        float lz = ((float)gk + 0.5f) / 6.0f * sz - sz * 0.5f;
        float c = cosf(roi[6]), s = sinf(roi[6]);
        gp[m * 3 + 0] = lx * c - ly * s + roi[0];
        gp[m * 3 + 1] = lx * s + ly * c + roi[1];
        gp[m * 3 + 2] = lz + roi[2];
    } else if (b < 150) {                // ---- weight prep (permuted transpose + hi/lo)
        int t = (b - 108) * 256 + tid;   // t < 10752
        {
            int col = t / 168, p = t % 168;
            float v = (p < 128) ? w1[(3 + p) * 64 + col]
                    : (p < 131) ? w1[(p - 128) * 64 + col] : 0.f;
            ushort_t hi = f2bf(v);
            w1th[t] = hi;
            w1tl[t] = f2bf(v - bf2f(hi));
        }
        if (t < 4608) {
            int col = t / 72, k = t % 72;
            float v = (k < 64) ? w2[k * 64 + col] : 0.f;
            ushort_t hi = f2bf(v);
            w2th[t] = hi;
            w2tl[t] = f2bf(v - bf2f(hi));
        }
    } else if (b < 2198) {               // ---- feats -> hi/lo bf16
        int i = (b - 150) * 256 + tid;   // i < 524288
        float v = feats[i];
        __bf16 h = (__bf16)v;
        fhi[i] = bfbits(h);
        flo[i] = bfbits((__bf16)(v - (float)h));
    } else if (b < 2214) {               // ---- xyz -> float4 pack
        int i = (b - 2198) * 256 + tid;  // i < 4096
        xyz4[i] = make_float4(xyz[i * 3 + 0], xyz[i * 3 + 1], xyz[i * 3 + 2], 0.f);
    } else {                             // ---- per-RoI candidate lists (4 waves/block)
        int r = (b - 2214) * 4 + (tid >> 6);
        int lane = tid & 63;
        const float* roi = rois + r * 7;
        float cx = roi[0], cy = roi[1], cz = roi[2];
        float sx = roi[3], sy = roi[4], sz = roi[5];
        float Rc = 0.8f + 0.4166667f * sqrtf(sx * sx + sy * sy + sz * sz) + 0.01f;
        float Rc2 = Rc * Rc;
        int* cl = cand + (size_t)r * N_PTS;
        int cnt = 0;
        for (int base = 0; base < N_PTS; base += 64) {
            int i = base + lane;
            float dx = xyz[i * 3 + 0] - cx;
            float dy = xyz[i * 3 + 1] - cy;
            float dz = xyz[i * 3 + 2] - cz;
            bool in = dx * dx + dy * dy + dz * dz < Rc2;
            unsigned long long ball = __ballot(in);
            int before = __popcll(ball & ((1ull << lane) - 1ull));
            if (in) cl[cnt + before] = i;
            cnt += __popcll(ball);
        }
        if (lane == 0) ncand[r] = cnt;
    }
}

// ---------------- F = feats @ W1f (split-bf16 MFMA), 4096x64 f32 ----------
__global__ __launch_bounds__(256) void f_gemm_k(
    const ushort_t* __restrict__ fhi, const ushort_t* __restrict__ flo,
    const ushort_t* __restrict__ w1th, const ushort_t* __restrict__ w1tl,
    float* __restrict__ F) {
    int tid = threadIdx.x;
    int w = tid >> 6, lane = tid & 63;
    int row = lane & 15, grp = lane >> 4;
    int m0 = blockIdx.x * 64 + w * 16;

    f32x4 acc[4];
#pragma unroll
    for (int nt = 0; nt < 4; nt++) acc[nt] = {0.f, 0.f, 0.f, 0.f};

#pragma unroll
    for (int ks = 0; ks < 4; ks++) {
        size_t ao = (size_t)(m0 + row) * 128 + ks * 32 + grp * 8;
        bf16x8 ah = *(const bf16x8*)&fhi[ao];
        bf16x8 al = *(const bf16x8*)&flo[ao];
#pragma unroll
        for (int nt = 0; nt < 4; nt++) {
            int bo = (nt * 16 + row) * 168 + ks * 32 + grp * 8;
            bf16x8 bh = *(const bf16x8*)&w1th[bo];
            bf16x8 bl = *(const bf16x8*)&w1tl[bo];
            acc[nt] = __builtin_amdgcn_mfma_f32_16x16x32_bf16(ah, bh, acc[nt], 0, 0, 0);
            acc[nt] = __builtin_amdgcn_mfma_f32_16x16x32_bf16(al, bh, acc[nt], 0, 0, 0);
            acc[nt] = __builtin_amdgcn_mfma_f32_16x16x32_bf16(ah, bl, acc[nt], 0, 0, 0);
        }
    }
#pragma unroll
    for (int nt = 0; nt < 4; nt++)
#pragma unroll
        for (int reg = 0; reg < 4; reg++)
            F[(size_t)(m0 + grp * 4 + reg) * 64 + nt * 16 + row] = acc[nt][reg];
}

// ---------------- pool v5: SHARED 4-gp scan + F-gather + stage2 MFMA -------
__global__ __launch_bounds__(64) void grid_pool_v5_k(
    const float4* __restrict__ xyz4, const float* __restrict__ F,
    const float* __restrict__ gp, const int* __restrict__ cand,
    const int* __restrict__ ncand, const float* __restrict__ w_m1,
    const ushort_t* __restrict__ w2th, const ushort_t* __restrict__ w2tl,
    ushort_t* __restrict__ Afh, ushort_t* __restrict__ Afl) {
    __shared__ int s_idx[4][16];
    int lane = threadIdx.x;
    const float R2 = (float)(0.8 * 0.8);
    int row = lane & 15, grp = lane >> 4;
    int m0 = blockIdx.x * 4;
    int r = m0 / 216;                    // shared RoI for all 4 gps

    float gxv[4], gyv[4], gzv[4];
#pragma unroll
    for (int g = 0; g < 4; g++) {
        int m = m0 + g;
        gxv[g] = gp[m * 3 + 0];
        gyv[g] = gp[m * 3 + 1];
        gzv[g] = gp[m * 3 + 2];
    }

    int nc = ncand[r];
    const int* cl = cand + (size_t)r * N_PTS;
    int cnt0 = 0, cnt1 = 0, cnt2 = 0, cnt3 = 0;
    for (int base = 0; base < nc; base += 64) {
        int t = base + lane;
        float px = 1e30f, py = 1e30f, pz = 1e30f;
        int i = 0;
        if (t < nc) {
            i = cl[t];
            float4 p = xyz4[i];
            px = p.x; py = p.y; pz = p.z;
        }
#pragma unroll
        for (int g = 0; g < 4; g++) {
            float dx = px - gxv[g], dy = py - gyv[g], dz = pz - gzv[g];
            bool in = dx * dx + dy * dy + dz * dz < R2;
            unsigned long long ball = __ballot(in);
            int before = __popcll(ball & ((1ull << lane) - 1ull));
            int cnt = (g == 0) ? cnt0 : (g == 1) ? cnt1 : (g == 2) ? cnt2 : cnt3;
            int pos = cnt + before;
            if (in && pos < 16) s_idx[g][pos] = i;
            int add = __popcll(ball);
            if (g == 0) cnt0 += add; else if (g == 1) cnt1 += add;
            else if (g == 2) cnt2 += add; else cnt3 += add;
        }
        if (cnt0 >= 16 && cnt1 >= 16 && cnt2 >= 16 && cnt3 >= 16) break;
    }
    LDS_FENCE();

    bool empty[4];
#pragma unroll
    for (int g = 0; g < 4; g++) {
        int cnt = (g == 0) ? cnt0 : (g == 1) ? cnt1 : (g == 2) ? cnt2 : cnt3;
        int c = min(cnt, 16);
        empty[g] = (c == 0);
        if (lane == 0) {
            if (c == 0) {
                for (int p = 0; p < 16; p++) s_idx[g][p] = 0;
            } else {
                int f = s_idx[g][0];
                for (int p = c; p < 16; p++) s_idx[g][p] = f;
            }
        }
    }
    LDS_FENCE();

    int pi[4];
    float rx[4], ry[4], rz[4];
#pragma unroll
    for (int g = 0; g < 4; g++) {
        pi[g] = s_idx[g][row];
        float4 p = xyz4[pi[g]];
        rx[g] = p.x - gxv[g];
        ry[g] = p.y - gyv[g];
        rz[g] = p.z - gzv[g];
    }

    f32x4 p[4][4];
#pragma unroll
    for (int g = 0; g < 4; g++)
#pragma unroll
        for (int nt = 0; nt < 4; nt++) p[g][nt] = {0.f, 0.f, 0.f, 0.f};

#pragma unroll
    for (int ks = 0; ks < 2; ks++) {
        float w1r0[8], w1r1[8], w1r2[8];
        {
            const float* wp = w_m1 + ks * 32 + grp * 8;
            *(float4*)&w1r0[0] = *(const float4*)(wp);
            *(float4*)&w1r0[4] = *(const float4*)(wp + 4);
            *(float4*)&w1r1[0] = *(const float4*)(wp + 64);
            *(float4*)&w1r1[4] = *(const float4*)(wp + 68);
            *(float4*)&w1r2[0] = *(const float4*)(wp + 128);
            *(float4*)&w1r2[4] = *(const float4*)(wp + 132);
        }
        bf16x8 zah[4], zal[4];
#pragma unroll
        for (int g = 0; g < 4; g++) {
            const float* Fr = F + (size_t)pi[g] * 64 + ks * 32 + grp * 8;
            float fv[8];
            *(float4*)&fv[0] = *(const float4*)Fr;
            *(float4*)&fv[4] = *(const float4*)(Fr + 4);
            bf16x8 hh, ll;
#pragma unroll
            for (int j = 0; j < 8; j++) {
                float zv = fv[j] + rx[g] * w1r0[j] + ry[g] * w1r1[j] + rz[g] * w1r2[j];
                float v = fmaxf(zv, 0.f);
                __bf16 h = (__bf16)v;
                hh[j] = h;
                ll[j] = (__bf16)(v - (float)h);
            }
            zah[g] = hh; zal[g] = ll;
        }
#pragma unroll
        for (int nt = 0; nt < 4; nt++) {
            int bo = (nt * 16 + row) * 72 + ks * 32 + grp * 8;
            bf16x8 bh = *(const bf16x8*)&w2th[bo];
            bf16x8 bl = *(const bf16x8*)&w2tl[bo];
#pragma unroll
            for (int g = 0; g < 4; g++) {
                p[g][nt] = __builtin_amdgcn_mfma_f32_16x16x32_bf16(zah[g], bh, p[g][nt], 0, 0, 0);
                p[g][nt] = __builtin_amdgcn_mfma_f32_16x16x32_bf16(zal[g], bh, p[g][nt], 0, 0, 0);
                p[g][nt] = __builtin_amdgcn_mfma_f32_16x16x32_bf16(zah[g], bl, p[g][nt], 0, 0, 0);
            }
        }
    }

#pragma unroll
    for (int g = 0; g < 4; g++) {
        int m = m0 + g;
        int t = m % 216;
#pragma unroll
        for (int nt = 0; nt < 4; nt++) {
            float mv = fmaxf(fmaxf(fmaxf(p[g][nt][0], p[g][nt][1]),
                                   fmaxf(p[g][nt][2], p[g][nt][3])), 0.f);
            mv = fmaxf(mv, __shfl_xor(mv, 16));
            mv = fmaxf(mv, __shfl_xor(mv, 32));
            if (grp == 0) {
                float v = empty[g] ? 0.f : mv;
                __bf16 h = (__bf16)v;
                int kt = t * 2 + (nt >> 1);
                size_t o = ((size_t)kt * 128 + r) * 32 + (nt & 1) * 16 + row;
                Afh[o] = bfbits(h);
                Afl[o] = bfbits((__bf16)(v - (float)h));
            }
        }
    }
}

// ---------------- generalized streaming split-K MFMA GEMM -------------------
// Identical to round 12 EXCEPT the pipeline uses NAMED register slots via a
// 2-unrolled main loop (rule #20: runtime-indexed register arrays spill to
// scratch — the round-12 bv[cur] did exactly that, 235us). STEPS must be even
// (54 / 4 / 8 / 8 here).
__global__ __launch_bounds__(256) void gemm_stream_k(
    const ushort_t* __restrict__ A_h, const ushort_t* __restrict__ A_l,
    size_t a_stride,
    const float* __restrict__ B0, const float* __restrict__ B1,
    const float* __restrict__ B2,
    float* __restrict__ P, int N, int Kt, int S) {
    __shared__ __attribute__((aligned(16))) ushort_t Bs_h[32][40];
    __shared__ __attribute__((aligned(16))) ushort_t Bs_l[32][40];
    int tid = threadIdx.x;
    int w = tid >> 6, lane = tid & 63;
    int row = lane & 15, grp = lane >> 4;
    int z = blockIdx.z, head = z / S, s = z % S;
    int n0 = blockIdx.x * 32, m0 = blockIdx.y * 64;
    const float* B = (head == 0) ? B0 : (head == 1) ? B1 : B2;
    const ushort_t* Ah = A_h + (size_t)head * a_stride;
    const ushort_t* Al = A_l + (size_t)head * a_stride;
    const int STEPS = Kt / (32 * S);     // even for all call sites
    int kt0 = s * STEPS;                 // in 32-k tile units
    int nl = tid & 31, kg = tid >> 5;    // staging: n = n0+nl, k = kg*4+j

    f32x4 acc0 = {0.f, 0.f, 0.f, 0.f};
    f32x4 acc1 = {0.f, 0.f, 0.f, 0.f};
    int arow = m0 + w * 16 + row;
    const float* bbase = B + ((size_t)kt0 * 32 + kg * 4) * N + n0 + nl;
    size_t abase = ((size_t)kt0 * 128 + arow) * 32 + grp * 8;

#define LOADB(t, dst)                                                         \
    do {                                                                      \
        const float* bp_ = bbase + (size_t)(t) * 32 * N;                      \
        dst.x = bp_[0];                                                       \
        dst.y = bp_[(size_t)N];                                               \
        dst.z = bp_[(size_t)2 * N];                                           \
        dst.w = bp_[(size_t)3 * N];                                           \
    } while (0)
#define LOADA(t, dh, dl)                                                      \
    do {                                                                      \
        size_t ao_ = abase + (size_t)(t) * 4096;                              \
        dh = *(const bf16x8*)&Ah[ao_];                                        \
        dl = *(const bf16x8*)&Al[ao_];                                        \
    } while (0)
#define STAGE(bv)                                                             \
    do {                                                                      \
        ushort_t hs0 = f2bf(bv.x), ls0;                                       \
        ls0 = f2bf(bv.x - bf2f(hs0));                                         \
        ushort_t hs1 = f2bf(bv.y), ls1;                                       \
        ls1 = f2bf(bv.y - bf2f(hs1));                                         \
        ushort_t hs2 = f2bf(bv.z), ls2;                                       \
        ls2 = f2bf(bv.z - bf2f(hs2));                                         \
        ushort_t hs3 = f2bf(bv.w), ls3;                                       \
        ls3 = f2bf(bv.w - bf2f(hs3));                                         \
        uint2 hw_ = make_uint2((unsigned)hs0 | ((unsigned)hs1 << 16),         \
                               (unsigned)hs2 | ((unsigned)hs3 << 16));        \
        uint2 lw_ = make_uint2((unsigned)ls0 | ((unsigned)ls1 << 16),         \
                               (unsigned)ls2 | ((unsigned)ls3 << 16));        \
        *(uint2*)&Bs_h[nl][kg * 4] = hw_;                                     \
        *(uint2*)&Bs_l[nl][kg * 4] = lw_;                                     \
    } while (0)
#define COMPUTE(ah_, al_)                                                     \
    do {                                                                      \
        bf16x8 bh0 = *(const bf16x8*)&Bs_h[row][grp * 8];                     \
        bf16x8 bl0 = *(const bf16x8*)&Bs_l[row][grp * 8];                     \
        acc0 = __builtin_amdgcn_mfma_f32_16x16x32_bf16(ah_, bh0, acc0, 0, 0, 0); \
        acc0 = __builtin_amdgcn_mfma_f32_16x16x32_bf16(al_, bh0, acc0, 0, 0, 0); \
        acc0 = __builtin_amdgcn_mfma_f32_16x16x32_bf16(ah_, bl0, acc0, 0, 0, 0); \
        bf16x8 bh1 = *(const bf16x8*)&Bs_h[16 + row][grp * 8];                \
        bf16x8 bl1 = *(const bf16x8*)&Bs_l[16 + row][grp * 8];                \
        acc1 = __builtin_amdgcn_mfma_f32_16x16x32_bf16(ah_, bh1, acc1, 0, 0, 0); \
        acc1 = __builtin_amdgcn_mfma_f32_16x16x32_bf16(al_, bh1, acc1, 0, 0, 0); \
        acc1 = __builtin_amdgcn_mfma_f32_16x16x32_bf16(ah_, bl1, acc1, 0, 0, 0); \
    } while (0)

    float4 bv0, bv1;
    bf16x8 a0h, a0l, a1h, a1l;
    LOADB(0, bv0);
    LOADA(0, a0h, a0l);
    LOADB(1, bv1);
    LOADA(1, a1h, a1l);

    for (int t = 0; t < STEPS; t += 2) {
        STAGE(bv0);
        __syncthreads();
        COMPUTE(a0h, a0l);
        if (t + 2 < STEPS) {             // refill slot 0 for iteration t+2
            LOADB(t + 2, bv0);
            LOADA(t + 2, a0h, a0l);
        }
        __syncthreads();
        STAGE(bv1);
        __syncthreads();
        COMPUTE(a1h, a1l);
        if (t + 3 < STEPS) {             // refill slot 1 for iteration t+3
            LOADB(t + 3, bv1);
            LOADA(t + 3, a1h, a1l);
        }
        __syncthreads();
    }
#undef LOADB
#undef LOADA
#undef STAGE
#undef COMPUTE

    size_t pb = (size_t)z * 128 * N;
#pragma unroll
    for (int reg = 0; reg < 4; reg++) {
        int mrow = m0 + w * 16 + grp * 4 + reg;
        P[pb + (size_t)mrow * N + n0 + row] = acc0[reg];
        P[pb + (size_t)mrow * N + n0 + 16 + row] = acc1[reg];
    }
}

// ---------------- reduce partials + relu -> frag-layout hi/lo (or f32) ----
__global__ __launch_bounds__(256) void reduce_frag_k(
    const float* __restrict__ P, ushort_t* __restrict__ C_h,
    ushort_t* __restrict__ C_l, float* __restrict__ C_f, int out_f32,
    int MNper, int S, int heads, int Nn) {
    int i = blockIdx.x * 256 + threadIdx.x;
    if (i >= heads * MNper) return;
    int h = i / MNper, j = i % MNper;
    float v = 0.f;
    for (int s = 0; s < S; s++) v += P[((size_t)(h * S + s)) * MNper + j];
    v = fmaxf(v, 0.f);
    if (out_f32) {
        C_f[i] = v;
        return;
    }
    int m = j / Nn, n = j % Nn;
    size_t off = (size_t)h * MNper + ((size_t)(n >> 5) * 128 + m) * 32 + (n & 31);
    __bf16 hh = (__bf16)v;
    C_h[off] = bfbits(hh);
    C_l[off] = bfbits((__bf16)(v - (float)hh));
}

// ---------------- final head projections (merged) ----------------
__global__ __launch_bounds__(256) void head_out3_k(
    const float* __restrict__ h2s, const float* __restrict__ w_c3,
    const float* __restrict__ w_i3, const float* __restrict__ w_r3,
    const float* __restrict__ b_c3, const float* __restrict__ b_i3,
    const float* __restrict__ b_r3, float* __restrict__ out) {
    int t = blockIdx.x * 256 + threadIdx.x;
    if (t >= 128 * 9) return;
    int r = t / 9, col = t % 9;
    int head = (col == 0) ? 0 : (col == 1) ? 1 : 2;
    int p = (col < 2) ? 0 : col - 2;
    int Pn = (head == 2) ? 7 : 1;
    const float* h2 = h2s + (size_t)head * (128 * 512) + (size_t)r * 512;
    const float* w3 = (head == 0) ? w_c3 : (head == 1) ? w_i3 : w_r3;
    float acc = ((head == 0) ? b_c3 : (head == 1) ? b_i3 : b_r3)[p];
    for (int j = 0; j < 512; j++) acc += h2[j] * w3[j * Pn + p];
    out[r * 9 + col] = acc;
}

extern "C" void kernel_launch(void* const* d_in, const int* in_sizes, int n_in,
                              void* d_out, int out_size, void* d_ws, size_t ws_size,
                              hipStream_t stream) {
    const float* xyz   = (const float*)d_in[0];
    const float* feats = (const float*)d_in[1];
    const float* rois  = (const float*)d_in[2];
    const float* w_m1  = (const float*)d_in[3];
    const float* w_m2  = (const float*)d_in[4];
    const float* w_s1  = (const float*)d_in[5];
    const float* w_s2  = (const float*)d_in[6];
    const float* w_c1  = (const float*)d_in[7];
    const float* w_c2  = (const float*)d_in[8];
    const float* w_c3  = (const float*)d_in[9];
    const float* b_c3  = (const float*)d_in[10];
    const float* w_i1  = (const float*)d_in[11];
    const float* w_i2  = (const float*)d_in[12];
    const float* w_i3  = (const float*)d_in[13];
    const float* b_i3  = (const float*)d_in[14];
    const float* w_r1  = (const float*)d_in[15];
    const float* w_r2  = (const float*)d_in[16];
    const float* w_r3  = (const float*)d_in[17];
    const float* b_r3  = (const float*)d_in[18];
    float* out = (float*)d_out;

    char* ws = (char*)d_ws;
    float*    gp     = (float*)(ws + OFF_GP);
    ushort_t* afh    = (ushort_t*)(ws + OFF_PH);
    ushort_t* afl    = (ushort_t*)(ws + OFF_PL);
    float*    part   = (float*)(ws + OFF_PART);
    int*      cand   = (int*)(ws + OFF_CAND);
    float*    F      = (float*)(ws + OFF_F);
    float4*   xyz4   = (float4*)(ws + OFF_XYZ4);
    int*      ncand  = (int*)(ws + OFF_NCAND);
    ushort_t* w1th   = (ushort_t*)(ws + OFF_W1TH);
    ushort_t* w1tl   = (ushort_t*)(ws + OFF_W1TL);
    ushort_t* w2th   = (ushort_t*)(ws + OFF_W2TH);
    ushort_t* w2tl   = (ushort_t*)(ws + OFF_W2TL);
    ushort_t* fhi    = (ushort_t*)(ws + OFF_FHI);
    ushort_t* flo    = (ushort_t*)(ws + OFF_FLO);
    ushort_t* t1h    = (ushort_t*)(ws + OFF_T1H);
    ushort_t* t1l    = (ushort_t*)(ws + OFF_T1L);
    ushort_t* sfch   = (ushort_t*)(ws + OFF_SFCH);
    ushort_t* sfcl   = (ushort_t*)(ws + OFF_SFCL);
    ushort_t* h1h    = (ushort_t*)(ws + OFF_H1H);
    ushort_t* h1l    = (ushort_t*)(ws + OFF_H1L);
    float*    h2s    = (float*)(ws + OFF_H2S);

    // 1. all prep
    hipLaunchKernelGGL(prep_all_k, dim3(2246), dim3(256), 0, stream,
                       rois, xyz, feats, w_m1, w_m2, gp, fhi, flo,
                       w1th, w1tl, w2th, w2tl, xyz4, cand, ncand);
    // 2. F = feats @ W1f
    hipLaunchKernelGGL(f_gemm_k, dim3(64), dim3(256), 0, stream,
                       fhi, flo, w1th, w1tl, F);
    // 3. pool -> A_frag hi/lo (shared 4-gp scan)
    hipLaunchKernelGGL(grid_pool_v5_k, dim3(M_GP / 4), dim3(64), 0, stream,
                       xyz4, F, gp, cand, ncand, w_m1, w2th, w2tl, afh, afl);
    // 4. s1: Afrag(13824) @ w_s1 -> partials (S=8, 512 blocks)
    hipLaunchKernelGGL(gemm_stream_k, dim3(32, 2, 8), dim3(256), 0, stream,
                       afh, afl, (size_t)0, w_s1, w_s1, w_s1, part, 1024, 13824, 8);
    hipLaunchKernelGGL(reduce_frag_k, dim3(512), dim3(256), 0, stream,
                       part, t1h, t1l, (float*)nullptr, 0, 128 * 1024, 8, 1, 1024);
    // 5. s2: t1frag(1024) @ w_s2 -> sfc frag (S=8, 256 blocks)
    hipLaunchKernelGGL(gemm_stream_k, dim3(16, 2, 8), dim3(256), 0, stream,
                       t1h, t1l, (size_t)0, w_s2, w_s2, w_s2, part, 512, 1024, 8);
    hipLaunchKernelGGL(reduce_frag_k, dim3(256), dim3(256), 0, stream,
                       part, sfch, sfcl, (float*)nullptr, 0, 128 * 512, 8, 1, 512);
    // 6. heads L1: sfcfrag(512) @ {w_c1,w_i1,w_r1} -> h1 frag (S=2, 384 blocks)
    hipLaunchKernelGGL(gemm_stream_k, dim3(32, 2, 6), dim3(256), 0, stream,
                       sfch, sfcl, (size_t)0, w_c1, w_i1, w_r1, part, 1024, 512, 2);
    hipLaunchKernelGGL(reduce_frag_k, dim3(1536), dim3(256), 0, stream,
                       part, h1h, h1l, (float*)nullptr, 0, 128 * 1024, 2, 3, 1024);
    // 7. heads L2: h1frag(1024) @ {w_c2,w_i2,w_r2} -> h2s f32 (S=4, 384 blocks)
    hipLaunchKernelGGL(gemm_stream_k, dim3(16, 2, 12), dim3(256), 0, stream,
                       h1h, h1l, (size_t)131072, w_c2, w_i2, w_r2, part, 512, 1024, 4);
    hipLaunchKernelGGL(reduce_frag_k, dim3(768), dim3(256), 0, stream,
                       part, (ushort_t*)nullptr, (ushort_t*)nullptr, h2s, 1,
                       128 * 512, 4, 3, 512);
    // 8. final projections
    hipLaunchKernelGGL(head_out3_k, dim3(5), dim3(256), 0, stream,
                       h2s, w_c3, w_i3, w_r3, b_c3, b_i3, b_r3, out);
}